// Round 8
// baseline (69.737 us; speedup 1.0000x reference)
//
#include <hip/hip_runtime.h>

#define N_CAND 8192
#define TILE   64                           // tile edge = wave width
#define NTILES (N_CAND / TILE)              // 128
#define NLIVE  (NTILES * (NTILES + 1) / 2)  // 8256 upper-triangle tiles
#define WPB    16                           // waves per block (1024 threads)
#define NBLK   256                          // 1 block/CU
#define NWAVE  (NBLK * WPB)                 // 4096 waves: 2 tiles each + 64 chunked strays

// ---------------------------------------------------------------------------
// R17: get the j-side broadcast OFF the VALU *and* LDS pipes entirely.
// Diagnosis of R15/R16 near-nulls: ds_read throughput is ~5.8cy/wave-op on a
// per-CU pipe; 12 LDS ops/iter x 516 iters/CU ~= 15us -- the LDS pipe became
// the bottleneck the moment we moved broadcast+rcp onto it. The only idle
// pipe is SMEM/scalar. So:
//  - prologue kernel materializes E[i]=2^(l*log2e) and RF[i]=(float)r in
//    workspace (2 x 32KB, L2-resident).
//  - pairs kernel reads the j-side via wave-uniform loads from global ->
//    compiler scalarizes to s_load batches (SMEM pipe, zero VALU/LDS/trans).
//    j-loop fully unrolled so offsets are immediates.
//  - reciprocal: 1-Newton integer-magic (3 VALU ops; rel err ~1.2e-3 ->
//    loss bias <= 4e-4, threshold 6.5e-3). Masked pairs cndmask'd to 0.
//  - per-pipe /4-pair iter: VALU ~72cy, trans 64cy, LDS 0. Model: ~4.5us
//    + ~2us prologue. Same proven tile/stray mapping; fused atomicAdd.
// ---------------------------------------------------------------------------

__device__ __forceinline__ void decode_t(int t, int& bi, int& bj) {
    int b = (int)((__builtin_sqrtf(8.0f * (float)t + 1.0f) - 1.0f) * 0.5f);
    while ((b + 1) * (b + 2) / 2 <= t) ++b;   // guard fp rounding
    while (b * (b + 1) / 2 > t)       --b;
    bj = b; bi = t - b * (b + 1) / 2;
}

// 1/x: integer-magic seed + ONE Newton step. e_new = e_seed^2 <= 1.2e-3.
__device__ __forceinline__ float rcp1(float x) {
    float y = __int_as_float(0x7EF311C3 - __float_as_int(x));
    return y * fmaf(-x, y, 2.0f);
}

template<bool DIAG>
__device__ __forceinline__ float tile_sum64(
    const float* __restrict__ E, const float* __restrict__ RF,
    const float* __restrict__ logits,
    int bi, int bj, int lane)
{
    const float LOG2E = 1.4426950408889634f;
    const float lis = logits[bi * TILE + lane] * LOG2E;
    const float rif = RF[bi * TILE + lane];
    const float Ei  = E [bi * TILE + lane];
    // wave-uniform j-side base pointers -> scalar (SMEM) loads, imm offsets
    const float* __restrict__ jE = E  + bj * TILE;
    const float* __restrict__ jR = RF + bj * TILE;

    float accL0 = 0.0f, accL1 = 0.0f, accL2 = 0.0f, accL3 = 0.0f;
    float accW0 = 0.0f, accW1 = 0.0f, accW2 = 0.0f, accW3 = 0.0f;

    #pragma unroll
    for (int jj = 0; jj < TILE; jj += 4) {
        const float Ej0 = jE[jj    ], rj0 = jR[jj    ];
        const float Ej1 = jE[jj + 1], rj1 = jR[jj + 1];
        const float Ej2 = jE[jj + 2], rj2 = jR[jj + 2];
        const float Ej3 = jE[jj + 3], rj3 = jR[jj + 3];

        // softplus(lj-li)/ln2 = log2(Ei+Ej) - lis  (lis term factored out)
        const float L0 = __builtin_amdgcn_logf(Ei + Ej0);
        const float L1 = __builtin_amdgcn_logf(Ei + Ej1);
        const float L2 = __builtin_amdgcn_logf(Ei + Ej2);
        const float L3 = __builtin_amdgcn_logf(Ei + Ej3);

        const float u0 = rcp1(rif + rj0);
        const float u1 = rcp1(rif + rj1);
        const float u2 = rcp1(rif + rj2);
        const float u3 = rcp1(rif + rj3);

        bool s0 = (rj0 > rif), s1 = (rj1 > rif), s2 = (rj2 > rif), s3 = (rj3 > rif);
        if (DIAG) {
            s0 = s0 && (jj     > lane);
            s1 = s1 && (jj + 1 > lane);
            s2 = s2 && (jj + 2 > lane);
            s3 = s3 && (jj + 3 > lane);
        }
        const float w0 = s0 ? u0 : 0.0f;
        const float w1 = s1 ? u1 : 0.0f;
        const float w2 = s2 ? u2 : 0.0f;
        const float w3 = s3 ? u3 : 0.0f;

        accL0 = fmaf(w0, L0, accL0);  accW0 += w0;
        accL1 = fmaf(w1, L1, accL1);  accW1 += w1;
        accL2 = fmaf(w2, L2, accL2);  accW2 += w2;
        accL3 = fmaf(w3, L3, accL3);  accW3 += w3;
    }

    const float aL = (accL0 + accL1) + (accL2 + accL3);
    const float aW = (accW0 + accW1) + (accW2 + accW3);
    return fmaf(-lis, aW, aL);
}

// generic rolled path for the 64 stray 16-col chunks (2.3% of work)
__device__ __forceinline__ float tile_sum_range(
    const float* __restrict__ E, const float* __restrict__ RF,
    const float* __restrict__ logits,
    int bi, int bj, int lane, int j0, int j1)
{
    const float LOG2E = 1.4426950408889634f;
    const float lis = logits[bi * TILE + lane] * LOG2E;
    const float rif = RF[bi * TILE + lane];
    const float Ei  = E [bi * TILE + lane];
    const float* __restrict__ jE = E  + bj * TILE;
    const float* __restrict__ jR = RF + bj * TILE;
    const bool diag = (bi == bj);

    float accL = 0.0f, accW = 0.0f;
    #pragma unroll 1
    for (int jj = j0; jj < j1; ++jj) {
        const float Ej  = jE[jj];
        const float rjf = jR[jj];
        const float L   = __builtin_amdgcn_logf(Ei + Ej);
        const float u   = rcp1(rif + rjf);
        const bool  sel = (rjf > rif) && (!diag || jj > lane);
        const float w   = sel ? u : 0.0f;
        accL = fmaf(w, L, accL);  accW += w;
    }
    return fmaf(-lis, accW, accL);
}

// prologue: E[i] = 2^(l_i * log2e), RF[i] = (float)r_i
__global__ __launch_bounds__(256) void ranknet_prep_kernel(
    const float* __restrict__ logits,
    const int*   __restrict__ rankings,
    float*       __restrict__ E,
    float*       __restrict__ RF)
{
    const int i = blockIdx.x * 256 + threadIdx.x;
    const float LOG2E = 1.4426950408889634f;
    E [i] = __builtin_amdgcn_exp2f(logits[i] * LOG2E);
    RF[i] = (float)rankings[i];
}

__global__ __launch_bounds__(1024, 4) void ranknet_pairs_kernel(
    const float* __restrict__ logits,
    const float* __restrict__ E,
    const float* __restrict__ RF,
    float*       __restrict__ out)
{
    const int tid  = threadIdx.x;
    const int lane = tid & 63;
    const int wave = tid >> 6;
    const int gw   = __builtin_amdgcn_readfirstlane((int)blockIdx.x * WPB + wave);

    float lacc = 0.0f;

    // two full tiles per wave: t = gw and gw + 4096
    #pragma unroll 1
    for (int k = 0; k < 2; ++k) {
        const int t = __builtin_amdgcn_readfirstlane(gw + k * NWAVE);
        int bi, bj; decode_t(t, bi, bj);
        if (bi == bj) lacc += tile_sum64<true >(E, RF, logits, bi, bj, lane);
        else          lacc += tile_sum64<false>(E, RF, logits, bi, bj, lane);
    }

    // stray 16-col chunk (tiles 8192..8255, chunk c owned by wave 16c+(c&3))
    {
        const int c = gw >> 4;
        if ((gw & 15) == (c & 3)) {
            int bi, bj; decode_t(2 * NWAVE + (c >> 2), bi, bj);
            const int j0 = (c & 3) * 16;
            lacc += tile_sum_range(E, RF, logits, bi, bj, lane, j0, j0 + 16);
        }
    }

    // wave reduce
    #pragma unroll
    for (int off = 32; off > 0; off >>= 1)
        lacc += __shfl_down(lacc, off, 64);

    __shared__ float s_w[WPB];
    if (lane == 0) s_w[wave] = lacc;
    __syncthreads();

    // block reduce + fused final accumulation (out[0] zeroed by harness memset)
    if (tid == 0) {
        float s = 0.0f;
        #pragma unroll
        for (int w = 0; w < WPB; ++w) s += s_w[w];
        const float LN2 = 0.6931471805599453f;
        atomicAdd(out, s * (LN2 / (float)N_CAND));
    }
}

extern "C" void kernel_launch(void* const* d_in, const int* in_sizes, int n_in,
                              void* d_out, int out_size, void* d_ws, size_t ws_size,
                              hipStream_t stream)
{
    const float* logits   = (const float*)d_in[0];
    const int*   rankings = (const int*)  d_in[1];
    float*       out      = (float*)d_out;
    float*       E        = (float*)d_ws;                 // 32 KB
    float*       RF       = (float*)d_ws + N_CAND;        // 32 KB

    ranknet_prep_kernel <<<dim3(N_CAND / 256), dim3(256), 0, stream>>>(logits, rankings, E, RF);
    ranknet_pairs_kernel<<<dim3(NBLK), dim3(1024), 0, stream>>>(logits, E, RF, out);
}

// Round 9
// 69.606 us; speedup vs baseline: 1.0019x; 1.0019x over previous
//
#include <hip/hip_runtime.h>
#include <hip/hip_fp16.h>

#define N_CAND 8192
#define TILE   64                           // tile edge = wave width
#define NTILES (N_CAND / TILE)              // 128
#define NLIVE  (NTILES * (NTILES + 1) / 2)  // 8256 upper-triangle tiles
#define WPB    16                           // waves per block (1024 threads)
#define NBLK   256                          // 1 block/CU
#define NWAVE  (NBLK * WPB)                 // 4096 waves: 2 tiles each + 64 chunked strays
#define RTAB   (2 * N_CAND)                 // 16384 rcp-table entries (ri+rj <= 16382)

// ---------------------------------------------------------------------------
// R18: restore best-measured config (R16, 68.2us) + ONE delta: pack the
// j-side stage as float2{Ej, rjf} and broadcast with a single ds_read_b64
// (was 2x ds_read_b32) -> LDS ops per 4-pair group 12 -> 8.
// Falsifiable: if R16 was LDS-issue-limited this is -2.5us; if the
// envelope/DVFS-ramp theory holds (5 designs invariant at 68-70) it is null
// and the floor gets declared next round.
// Math identical to R16: 2-trans/pair (exp2 hoisted, -lis factored), fp16
// LDS rcp table (rel err 4.9e-4 -> loss err ~1.6e-4 << 6.5e-3; measured
// absmax 0.0 in R16), float-domain rank compare (exact for ints < 2^24).
// ---------------------------------------------------------------------------
__device__ __forceinline__ float tile_range_sum(
    const float* __restrict__ logits, const int* __restrict__ rankings,
    const __half* __restrict__ rcp_tab,
    float2* __restrict__ sEjR,
    int t, int lane, int j0, int j1)
{
    // invert t = bj*(bj+1)/2 + bi, 0 <= bi <= bj < NTILES  (wave-uniform)
    t = __builtin_amdgcn_readfirstlane(t);
    int bj = (int)((__builtin_sqrtf(8.0f * (float)t + 1.0f) - 1.0f) * 0.5f);
    while ((bj + 1) * (bj + 2) / 2 <= t) ++bj;   // guard fp rounding
    while (bj * (bj + 1) / 2 > t)       --bj;
    const int bi = t - bj * (bj + 1) / 2;

    const float LOG2E = 1.4426950408889634f;

    const float lis = logits[bi * TILE + lane] * LOG2E;
    const int   ri  = rankings[bi * TILE + lane];
    const float rif = (float)ri;
    const float ljs = logits[bj * TILE + lane] * LOG2E;
    const int   rj  = rankings[bj * TILE + lane];

    // exp2 hoisted: log2(Ei+Ej) - lis == softplus(lj-li)/ln2
    const float Ei = __builtin_amdgcn_exp2f(lis);
    sEjR[lane] = make_float2(__builtin_amdgcn_exp2f(ljs), (float)rj);
    // same-wave LDS RAW -> lgkmcnt, no barrier needed

    // per-lane row base into the rcp table (hoists ri out of the loop)
    const __half* __restrict__ rowp = rcp_tab + ri;

    float accL0 = 0.0f, accL1 = 0.0f, accL2 = 0.0f, accL3 = 0.0f;
    float accW0 = 0.0f, accW1 = 0.0f, accW2 = 0.0f, accW3 = 0.0f;

    if (bi != bj) {
        #pragma unroll 1
        for (int jj = j0; jj < j1; jj += 4) {
            // wave-uniform ds_read_b64 broadcasts: {Ej, rjf} in one op
            const float2 a0 = sEjR[jj    ], a1 = sEjR[jj + 1];
            const float2 a2 = sEjR[jj + 2], a3 = sEjR[jj + 3];

            const float L0 = __builtin_amdgcn_logf(Ei + a0.x);
            const float L1 = __builtin_amdgcn_logf(Ei + a1.x);
            const float L2 = __builtin_amdgcn_logf(Ei + a2.x);
            const float L3 = __builtin_amdgcn_logf(Ei + a3.x);

            const float u0 = __half2float(rowp[(int)a0.y]);  // 1/(ri+rj)
            const float u1 = __half2float(rowp[(int)a1.y]);
            const float u2 = __half2float(rowp[(int)a2.y]);
            const float u3 = __half2float(rowp[(int)a3.y]);

            const float w0 = (a0.y > rif) ? u0 : 0.0f;   // masked inf discarded
            const float w1 = (a1.y > rif) ? u1 : 0.0f;
            const float w2 = (a2.y > rif) ? u2 : 0.0f;
            const float w3 = (a3.y > rif) ? u3 : 0.0f;

            accL0 = fmaf(w0, L0, accL0);  accW0 += w0;
            accL1 = fmaf(w1, L1, accL1);  accW1 += w1;
            accL2 = fmaf(w2, L2, accL2);  accW2 += w2;
            accL3 = fmaf(w3, L3, accL3);  accW3 += w3;
        }
    } else {
        // diagonal tile: also require j > i (jj > lane)
        #pragma unroll 1
        for (int jj = j0; jj < j1; jj += 4) {
            const float2 a0 = sEjR[jj    ], a1 = sEjR[jj + 1];
            const float2 a2 = sEjR[jj + 2], a3 = sEjR[jj + 3];

            const float L0 = __builtin_amdgcn_logf(Ei + a0.x);
            const float L1 = __builtin_amdgcn_logf(Ei + a1.x);
            const float L2 = __builtin_amdgcn_logf(Ei + a2.x);
            const float L3 = __builtin_amdgcn_logf(Ei + a3.x);

            const float u0 = __half2float(rowp[(int)a0.y]);
            const float u1 = __half2float(rowp[(int)a1.y]);
            const float u2 = __half2float(rowp[(int)a2.y]);
            const float u3 = __half2float(rowp[(int)a3.y]);

            const float w0 = ((jj     > lane) && (a0.y > rif)) ? u0 : 0.0f;
            const float w1 = ((jj + 1 > lane) && (a1.y > rif)) ? u1 : 0.0f;
            const float w2 = ((jj + 2 > lane) && (a2.y > rif)) ? u2 : 0.0f;
            const float w3 = ((jj + 3 > lane) && (a3.y > rif)) ? u3 : 0.0f;

            accL0 = fmaf(w0, L0, accL0);  accW0 += w0;
            accL1 = fmaf(w1, L1, accL1);  accW1 += w1;
            accL2 = fmaf(w2, L2, accL2);  accW2 += w2;
            accL3 = fmaf(w3, L3, accL3);  accW3 += w3;
        }
    }

    const float accL = (accL0 + accL1) + (accL2 + accL3);
    const float accW = (accW0 + accW1) + (accW2 + accW3);
    return fmaf(-lis, accW, accL);   // factored -lis term, per lane
}

__global__ __launch_bounds__(1024, 4) void ranknet_fused_kernel(
    const float* __restrict__ logits,
    const int*   __restrict__ rankings,
    float*       __restrict__ out)
{
    __shared__ __half s_rcp[RTAB];        // 32 KB fp16 reciprocal table
    __shared__ float2 s_EjR[WPB][TILE];   // 8 KB packed j-side stage
    __shared__ float  s_w[WPB];

    const int tid  = threadIdx.x;
    const int lane = tid & 63;
    const int wave = tid >> 6;
    const int gw   = __builtin_amdgcn_readfirstlane((int)blockIdx.x * WPB + wave);

    // build rcp table: 16 entries per thread; entry 0 = inf (always masked)
    #pragma unroll
    for (int k = 0; k < RTAB / 1024; ++k) {
        const int idx = tid + k * 1024;
        s_rcp[idx] = __float2half(__builtin_amdgcn_rcpf((float)idx));
    }
    __syncthreads();

    float lacc = 0.0f;
    // k=0: tile gw; k=1: tile gw+4096; k=2: stray 16-col chunk if owned.
    #pragma unroll 1
    for (int k = 0; k < 3; ++k) {
        int tt, jj0, jj1;
        bool live = true;
        if (k == 0)      { tt = gw;          jj0 = 0; jj1 = TILE; }
        else if (k == 1) { tt = gw + NWAVE;  jj0 = 0; jj1 = TILE; }
        else {
            const int c = gw >> 4;                    // chunk id, c < 256
            live = ((gw & 15) == (c & 3));            // wave 16c+(c&3) owns chunk c
            tt   = 2 * NWAVE + (c >> 2);              // stray tile 8192 + c/4
            jj0  = (c & 3) * 16;                      // 16-column chunk
            jj1  = jj0 + 16;
        }
        if (live)
            lacc += tile_range_sum(logits, rankings, s_rcp,
                                   s_EjR[wave], tt, lane, jj0, jj1);
    }

    // wave reduce
    #pragma unroll
    for (int off = 32; off > 0; off >>= 1)
        lacc += __shfl_down(lacc, off, 64);
    if (lane == 0) s_w[wave] = lacc;
    __syncthreads();

    // block reduce + fused final accumulation (out[0] zeroed by harness memset)
    if (tid == 0) {
        float s = 0.0f;
        #pragma unroll
        for (int w = 0; w < WPB; ++w) s += s_w[w];
        const float LN2 = 0.6931471805599453f;
        atomicAdd(out, s * (LN2 / (float)N_CAND));
    }
}

extern "C" void kernel_launch(void* const* d_in, const int* in_sizes, int n_in,
                              void* d_out, int out_size, void* d_ws, size_t ws_size,
                              hipStream_t stream)
{
    const float* logits   = (const float*)d_in[0];
    const int*   rankings = (const int*)  d_in[1];
    float*       out      = (float*)d_out;
    (void)d_ws; (void)ws_size;

    ranknet_fused_kernel<<<dim3(NBLK), dim3(1024), 0, stream>>>(logits, rankings, out);
}